// Round 3
// baseline (1651.454 us; speedup 1.0000x reference)
//
#include <hip/hip_runtime.h>
#include <stdint.h>

#define N_NODES 100000
#define N_EDGES 3200000
#define IN_DIM  512
#define HID     256
#define NCLS    16

// graph-prep histogram geometry
#define DBLK   256                   // blocks (one per CU)
#define DCHUNK (N_EDGES / DBLK)      // 12500 edges per block
#define DWIN2  50000                 // nodes per LDS window in hist (byte counters, 100 KB)

// phased aggregation geometry
#define AG_G   16                    // column phases
#define AG_C   16                    // columns per phase (32 B per row-slice)
#define AG_RPB 16                    // rows per block (16 waves of 1024 threads)

typedef unsigned short u16;
typedef __attribute__((ext_vector_type(8))) short short8;
typedef __attribute__((ext_vector_type(4))) float float4v;

// ---------------- bf16 helpers ----------------
__device__ __forceinline__ float bf2f(u16 u) {
  return __uint_as_float(((uint32_t)u) << 16);
}
__device__ __forceinline__ u16 f2bf(float f) {   // round-to-nearest-even
  uint32_t u = __float_as_uint(f);
  return (u16)((u + 0x7fffu + ((u >> 16) & 1u)) >> 16);
}

// ---------------- Threefry-2x32 (exact JAX schedule, partitionable mode) ----------------
__host__ __device__ __forceinline__ uint32_t rotl32(uint32_t v, int d) {
  return (v << d) | (v >> (32 - d));
}

__host__ __device__ __forceinline__ void threefry2x32(uint32_t k0, uint32_t k1,
    uint32_t x0, uint32_t x1, uint32_t& o0, uint32_t& o1) {
  uint32_t ks0 = k0, ks1 = k1, ks2 = k0 ^ k1 ^ 0x1BD11BDAu;
  x0 += ks0; x1 += ks1;
#define TF_R(r) { x0 += x1; x1 = rotl32(x1, r); x1 ^= x0; }
  TF_R(13) TF_R(15) TF_R(26) TF_R(6)
  x0 += ks1; x1 += ks2 + 1u;
  TF_R(17) TF_R(29) TF_R(16) TF_R(24)
  x0 += ks2; x1 += ks0 + 2u;
  TF_R(13) TF_R(15) TF_R(26) TF_R(6)
  x0 += ks0; x1 += ks1 + 3u;
  TF_R(17) TF_R(29) TF_R(16) TF_R(24)
  x0 += ks1; x1 += ks2 + 4u;
  TF_R(13) TF_R(15) TF_R(26) TF_R(6)
  x0 += ks2; x1 += ks0 + 5u;
#undef TF_R
  o0 = x0; o1 = x1;
}

__host__ __device__ __forceinline__ uint32_t tf_bits32(uint32_t k0, uint32_t k1, uint32_t idx) {
  uint32_t o0, o1;
  threefry2x32(k0, k1, 0u, idx, o0, o1);
  return o0 ^ o1;
}

// ---------------- erfinv: XLA/Giles f32 polynomial ----------------
__device__ __forceinline__ float erfinv_f32(float x) {
  float w = -log1pf(-x * x);
  float p;
  if (w < 5.0f) {
    w -= 2.5f;
    p = 2.81022636e-08f;
    p = fmaf(p, w, 3.43273939e-07f);
    p = fmaf(p, w, -3.5233877e-06f);
    p = fmaf(p, w, -4.39150654e-06f);
    p = fmaf(p, w, 0.00021858087f);
    p = fmaf(p, w, -0.00125372503f);
    p = fmaf(p, w, -0.00417768164f);
    p = fmaf(p, w, 0.246640727f);
    p = fmaf(p, w, 1.50140941f);
  } else {
    w = sqrtf(w) - 3.0f;
    p = -0.000200214257f;
    p = fmaf(p, w, 0.000100950558f);
    p = fmaf(p, w, 0.00134934322f);
    p = fmaf(p, w, -0.00367342844f);
    p = fmaf(p, w, 0.00573950773f);
    p = fmaf(p, w, -0.0076224613f);
    p = fmaf(p, w, 0.00943887047f);
    p = fmaf(p, w, 1.00167406f);
    p = fmaf(p, w, 2.83297682f);
  }
  return p * x;
}

// ---------------- graph prep: privatized histogram, no global atomics ----------------
// P16[b][node] u16: lo8 = out-count, hi8 = in-count of block b's edge chunk.
// hist: 2 windows of 50000 nodes, byte-packed counters in u32 words
// (per-(block,node) counts are Poisson(0.125); max ~8 << 255, no cross-byte carry)
__global__ __launch_bounds__(1024) void hist_k(
    const int* __restrict__ esrc, const int* __restrict__ edst,
    u16* __restrict__ P16) {
  __shared__ uint32_t h32[DWIN2 / 2];   // 25000 u32 = 100 KB, 2 nodes per word
  const int b = blockIdx.x, tid = threadIdx.x;
  const int ebase = b * DCHUNK;
  for (int w = 0; w < 2; ++w) {
    const int lo = w * DWIN2;
    for (int i = tid; i < DWIN2 / 2; i += 1024) h32[i] = 0u;
    __syncthreads();
    for (int e = ebase + tid; e < ebase + DCHUNK; e += 1024) {
      int s = esrc[e], d = edst[e];
      unsigned su = (unsigned)(s - lo);
      if (su < (unsigned)DWIN2) atomicAdd(&h32[su >> 1], 1u << ((su & 1) * 16));
      unsigned du = (unsigned)(d - lo);
      if (du < (unsigned)DWIN2) atomicAdd(&h32[du >> 1], 0x100u << ((du & 1) * 16));
    }
    __syncthreads();
    for (int i = tid; i < DWIN2 / 2; i += 1024) {
      // word: [out_even | in_even<<8 | out_odd<<16 | in_odd<<24] == two P16 entries
      *(uint32_t*)(P16 + (size_t)b * N_NODES + lo + 2 * i) = h32[i];
    }
    __syncthreads();
  }
}

// column-sum partials -> degrees + inv-sqrt; rewrite P16[b][n] with exclusive in-prefix
__global__ void degsum_k(u16* __restrict__ P16, int* __restrict__ ind,
                         float* __restrict__ out_is, float* __restrict__ in_is) {
  int n = blockIdx.x * 256 + threadIdx.x;
  if (n >= N_NODES) return;
  uint32_t to = 0, ti = 0;
#pragma unroll 8
  for (int b = 0; b < DBLK; ++b) {
    uint32_t v = P16[(size_t)b * N_NODES + n];
    P16[(size_t)b * N_NODES + n] = (u16)ti;   // in-prefix: CSR slot base for (b, n)
    to += v & 0xffu; ti += v >> 8;
  }
  ind[n] = (int)ti;
  out_is[n] = rsqrtf(fmaxf((float)to, 1.0f));
  in_is[n]  = rsqrtf(fmaxf((float)ti, 1.0f));
}

// coalesced single-block tile scan: row_ofs = exclusive prefix of ind
__global__ __launch_bounds__(1024) void scan_offsets_k(
    const int* __restrict__ ind, int* __restrict__ row_ofs) {
  __shared__ int wsum[16];
  const int tid = threadIdx.x;
  const int lane = tid & 63, wv = tid >> 6;
  int running = 0;
  for (int base = 0; base < N_NODES; base += 1024) {
    const int i = base + tid;
    int v = (i < N_NODES) ? ind[i] : 0;
    int sc = v;
#pragma unroll
    for (int d = 1; d < 64; d <<= 1) {
      int t = __shfl_up(sc, d, 64);
      if (lane >= d) sc += t;
    }
    if (lane == 63) wsum[wv] = sc;
    __syncthreads();
    if (wv == 0) {
      int t = (lane < 16) ? wsum[lane] : 0;
#pragma unroll
      for (int d = 1; d < 16; d <<= 1) {
        int u = __shfl_up(t, d, 64);
        if (lane >= d) t += u;
      }
      if (lane < 16) wsum[lane] = t;   // inclusive scan of wave sums
    }
    __syncthreads();
    int wbase = (wv > 0) ? wsum[wv - 1] : 0;
    if (i < N_NODES) row_ofs[i] = running + wbase + sc - v;
    running += wsum[15];
    __syncthreads();   // protect wsum before next tile overwrites it
  }
  if (tid == 0) row_ofs[N_NODES] = running;
}

// atomic-free CSR placement, single window: u8-packed LDS cursors for all 100K nodes.
// slot = row_ofs[d] + P16[b][d] + per-block byte cursor (per-(block,node) count <= ~8)
__global__ __launch_bounds__(1024) void place_k(
    const int* __restrict__ esrc, const int* __restrict__ edst,
    const u16* __restrict__ P16, const int* __restrict__ row_ofs,
    int* __restrict__ csr) {
  __shared__ uint32_t cur32[N_NODES / 4];   // 25000 u32 = 100 KB, 4 nodes per word
  const int b = blockIdx.x, tid = threadIdx.x;
  for (int i = tid; i < N_NODES / 4; i += 1024) cur32[i] = 0u;
  __syncthreads();
  const int ebase = b * DCHUNK;
  for (int e = ebase + tid; e < ebase + DCHUNK; e += 1024) {
    int d = edst[e];
    int base = row_ofs[d] + (int)P16[(size_t)b * N_NODES + d];
    uint32_t old = atomicAdd(&cur32[d >> 2], 1u << ((d & 3) * 8));
    int c = (int)((old >> ((d & 3) * 8)) & 0xffu);
    csr[base + c] = esrc[e];
  }
}

// ---------------- dropout mask bits for hidden layer (1 bit per element) ----------------
__global__ void gen_mask_k(uint32_t k0, uint32_t k1, uint32_t* __restrict__ mask) {
  uint32_t idx = blockIdx.x * blockDim.x + threadIdx.x;   // exact grid = size
  uint32_t bits = tf_bits32(k0, k1, idx);
  unsigned long long bal = __ballot((bits >> 31) == 0u);  // keep := u < 0.5
  if ((threadIdx.x & 63) == 0) {
    uint32_t w = idx >> 5;
    mask[w] = (uint32_t)bal;
    mask[w + 1] = (uint32_t)(bal >> 32);
  }
}

// ---------------- Xb = bf16(dropout1(x) * 2 * out_is) ----------------
__global__ __launch_bounds__(256) void cast_x_k(
    const float* __restrict__ x, const float* __restrict__ out_is,
    uint32_t k0, uint32_t k1, u16* __restrict__ Xb) {
  uint32_t t = blockIdx.x * 256u + threadIdx.x;   // 6.4M threads, 8 elems each
  uint32_t idx = t * 8u;
  uint32_t row = idx >> 9;
  float sc = 2.0f * out_is[row];
  float4 v0 = *(const float4*)(x + idx);
  float4 v1 = *(const float4*)(x + idx + 4);
  float vv[8] = {v0.x, v0.y, v0.z, v0.w, v1.x, v1.y, v1.z, v1.w};
  u16 o[8];
#pragma unroll
  for (int j = 0; j < 8; ++j) {
    uint32_t bits = tf_bits32(k0, k1, idx + (uint32_t)j);
    float val = (bits >> 31) ? 0.0f : vv[j] * sc;
    o[j] = f2bf(val);
  }
  uint4 pk;
  pk.x = (uint32_t)o[0] | ((uint32_t)o[1] << 16);
  pk.y = (uint32_t)o[2] | ((uint32_t)o[3] << 16);
  pk.z = (uint32_t)o[4] | ((uint32_t)o[5] << 16);
  pk.w = (uint32_t)o[6] | ((uint32_t)o[7] << 16);
  *(uint4*)(Xb + idx) = pk;
}

// ---------------- W1t = bf16(W1^T)  [256][512] ----------------
__global__ void cast_w1_k(const float* __restrict__ W1, u16* __restrict__ W1t) {
  int idx = blockIdx.x * blockDim.x + threadIdx.x;   // exact grid = 512*256
  int k = idx >> 8, n = idx & 255;
  W1t[n * IN_DIM + k] = f2bf(W1[idx]);
}

// ---------------- Wt23 = bf16([W2^T ; W3^T])  [32][256] ----------------
__global__ void cast_w23_k(const float* __restrict__ W2, const float* __restrict__ W3,
                           u16* __restrict__ Wt23) {
  int idx = blockIdx.x * blockDim.x + threadIdx.x;   // exact grid = 32*256
  int n = idx >> 8, k = idx & 255;
  float v = (n < 16) ? W2[k * NCLS + n] : W3[k * NCLS + (n - 16)];
  Wt23[n * HID + k] = f2bf(v);
}

// ---------------- GEMM1 (MFMA bf16): X1b = Xb @ W1  [100000,512]x[512,256] -> bf16 ----------------
#define LDA 40   // ushort stride (80 B: 16B-aligned rows, dword-stride 20 -> <=2-way bank alias)
__global__ __launch_bounds__(256) void gemm1_k(
    const u16* __restrict__ Xb, const u16* __restrict__ W1t, u16* __restrict__ X1b) {
  __shared__ u16 As[64 * LDA];    // [row][k0..31]
  __shared__ u16 Bs[256 * LDA];   // [n][k0..31]
  const int tid = threadIdx.x;
  const int w = tid >> 6, l = tid & 63;
  const int m16 = l & 15, q = l >> 4;
  const long base_row = (long)blockIdx.x * 64;

  float4v acc[4][4];
#pragma unroll
  for (int i = 0; i < 4; ++i)
#pragma unroll
    for (int j = 0; j < 4; ++j) acc[i][j] = (float4v)0.0f;

  const int arow = tid >> 2, ac = tid & 3;   // A staging: 64 rows x 4 chunks(8 bf16)
  const long agr = base_row + arow;

  for (int k0 = 0; k0 < IN_DIM; k0 += 32) {
    uint4 va = make_uint4(0, 0, 0, 0);
    if (agr < N_NODES) va = *(const uint4*)(Xb + agr * IN_DIM + k0 + ac * 8);
    *(uint4*)(As + arow * LDA + ac * 8) = va;
#pragma unroll
    for (int c = 0; c < 4; ++c) {   // B staging: n = tid, 32 bf16 per row (L2-resident W1t)
      uint4 vb = *(const uint4*)(W1t + (size_t)tid * IN_DIM + k0 + c * 8);
      *(uint4*)(Bs + tid * LDA + c * 8) = vb;
    }
    __syncthreads();
    short8 a[4], b[4];
#pragma unroll
    for (int rt = 0; rt < 4; ++rt)
      a[rt] = *(const short8*)(As + (rt * 16 + m16) * LDA + q * 8);
#pragma unroll
    for (int ct = 0; ct < 4; ++ct)
      b[ct] = *(const short8*)(Bs + ((w * 4 + ct) * 16 + m16) * LDA + q * 8);
#pragma unroll
    for (int rt = 0; rt < 4; ++rt)
#pragma unroll
      for (int ct = 0; ct < 4; ++ct)
        acc[rt][ct] = __builtin_amdgcn_mfma_f32_16x16x32_bf16(a[rt], b[ct], acc[rt][ct], 0, 0, 0);
    __syncthreads();
  }
#pragma unroll
  for (int rt = 0; rt < 4; ++rt) {
#pragma unroll
    for (int r = 0; r < 4; ++r) {
      long grow = base_row + rt * 16 + q * 4 + r;
      if (grow < N_NODES) {
#pragma unroll
        for (int ct = 0; ct < 4; ++ct)
          X1b[grow * HID + (w * 4 + ct) * 16 + m16] = f2bf(acc[rt][ct][r]);
      }
    }
  }
}

// ---------------- column-phased CSR gather-sum (bf16) + relu -> h1 bf16 ----------------
// Phase g (blockIdx-major) aggregates ALL rows over columns [g*16, g*16+16).
// Hot X1b slice per phase = 100000*32B = 3.2 MB -> fits per-XCD L2; reuse becomes L2 hits.
// One wave per row per phase: 8 lanes per edge (4B/lane), 8 edges in flight.
__global__ __launch_bounds__(1024) void agg_relu_k(
    const u16* __restrict__ X1b, const int* __restrict__ row_ofs,
    const int* __restrict__ csr, const float* __restrict__ in_is,
    u16* __restrict__ h1b) {
  const int b = blockIdx.x;
  const int g = b / (N_NODES / AG_RPB);        // phase 0..15 (dispatch-order major)
  const int rb = b % (N_NODES / AG_RPB);
  const int wv = threadIdx.x >> 6, lane = threadIdx.x & 63;
  const int d = rb * AG_RPB + wv;              // this wave's dst row
  const int sub = lane >> 3;                   // edge subgroup 0..7
  const int col = g * AG_C + (lane & 7) * 2;   // this lane's column pair
  const int beg = row_ofs[d], end = row_ofs[d + 1];
  float a0 = 0.f, a1 = 0.f;
  int e0 = beg;
#pragma unroll 2
  for (; e0 + 15 < end; e0 += 16) {            // 16 edges: 2 independent gathers/lane
    int sA = csr[e0 + sub];
    int sB = csr[e0 + 8 + sub];
    uint32_t vA = *(const uint32_t*)(X1b + (size_t)sA * HID + col);
    uint32_t vB = *(const uint32_t*)(X1b + (size_t)sB * HID + col);
    a0 += bf2f((u16)(vA & 0xffffu)); a1 += bf2f((u16)(vA >> 16));
    a0 += bf2f((u16)(vB & 0xffffu)); a1 += bf2f((u16)(vB >> 16));
  }
  for (; e0 < end; e0 += 8) {                  // masked tail, 8 edges per pass
    int e = e0 + sub;
    if (e < end) {
      uint32_t v = *(const uint32_t*)(X1b + (size_t)csr[e] * HID + col);
      a0 += bf2f((u16)(v & 0xffffu)); a1 += bf2f((u16)(v >> 16));
    }
  }
  // reduce across the 8 edge-subgroups (lane bits 3..5)
#pragma unroll
  for (int m = 8; m < 64; m <<= 1) {
    a0 += __shfl_xor(a0, m, 64);
    a1 += __shfl_xor(a1, m, 64);
  }
  if (sub == 0) {                              // lanes 0..7 hold the 16 final columns
    float is = in_is[d];
    uint32_t pk = (uint32_t)f2bf(fmaxf(a0 * is, 0.0f)) |
                  ((uint32_t)f2bf(fmaxf(a1 * is, 0.0f)) << 16);
    *(uint32_t*)(h1b + (size_t)d * HID + col) = pk;
  }
}

// ---------------- BatchNorm stats (bf16 in, fp32 accumulate) ----------------
__global__ void bn_stats_k(const u16* __restrict__ h1b, float* __restrict__ bn) {
  int c = threadIdx.x;  // 256 threads
  float s = 0.f, s2 = 0.f;
  for (int r = blockIdx.x; r < N_NODES; r += gridDim.x) {
    float v = bf2f(h1b[(size_t)r * HID + c]);
    s += v; s2 += v * v;
  }
  atomicAdd(&bn[c], s);
  atomicAdd(&bn[HID + c], s2);
}

__global__ void bn_fin_k(float* __restrict__ bn) {
  int c = threadIdx.x;
  float mean = bn[c] / (float)N_NODES;
  float var = bn[HID + c] / (float)N_NODES - mean * mean;
  float istd = rsqrtf(var + 1e-5f);
  bn[512 + c] = istd;           // cB
  bn[768 + c] = -mean * istd;   // cA:  normalized = h*cB + cA
}

// ---------------- GEMM2/3 (MFMA): XMLV[row] = [mu(16) | logvar(16)] bf16 ----------------
#define WLS 264   // u16 row stride for Wls: dword-stride 132 -> 2-way bank alias (free)
__global__ __launch_bounds__(256) void gemm23_k(
    const u16* __restrict__ h1b, const u16* __restrict__ Wt23,
    const uint32_t* __restrict__ mask2a, const uint32_t* __restrict__ mask2b,
    const float* __restrict__ out_is, const float* __restrict__ bn,
    u16* __restrict__ XMLV) {
  __shared__ u16 Wls[32 * WLS];
  __shared__ float cB[HID], cA[HID];
  const int tid = threadIdx.x;
#pragma unroll
  for (int i = 0; i < 4; ++i) {   // stage Wt23 (16KB) into padded LDS
    int idx = tid + i * 256;      // 1024 uint4 chunks
    int n = idx >> 5, c = idx & 31;
    *(uint4*)(Wls + n * WLS + c * 8) = ((const uint4*)Wt23)[idx];
  }
  cB[tid] = bn[512 + tid];
  cA[tid] = bn[768 + tid];
  __syncthreads();

  const int wv = tid >> 6, lane = tid & 63;
  const int m = lane & 15, q = lane >> 4;
  const long arow = (long)blockIdx.x * 64 + wv * 16 + m;   // A row this lane loads
  const bool valid = arow < N_NODES;
  const float osc = valid ? 2.0f * out_is[arow] : 0.0f;

  float4v accM = (float4v)0.0f, accL = (float4v)0.0f;
  for (int kc = 0; kc < HID; kc += 32) {
    const int kof = kc + q * 8;
    uint4 hv = make_uint4(0, 0, 0, 0);
    uint32_t wa = 0, wb = 0;
    if (valid) {
      hv = *(const uint4*)(h1b + arow * HID + kof);
      uint32_t widx = ((uint32_t)arow * HID + (uint32_t)kc) >> 5;
      wa = mask2a[widx] >> (q * 8);
      wb = mask2b[widx] >> (q * 8);
    }
    float4 B0 = *(const float4*)(cB + kof);
    float4 B1 = *(const float4*)(cB + kof + 4);
    float4 A0 = *(const float4*)(cA + kof);
    float4 A1 = *(const float4*)(cA + kof + 4);
    float hval[8] = {
      bf2f((u16)(hv.x & 0xffffu)), bf2f((u16)(hv.x >> 16)),
      bf2f((u16)(hv.y & 0xffffu)), bf2f((u16)(hv.y >> 16)),
      bf2f((u16)(hv.z & 0xffffu)), bf2f((u16)(hv.z >> 16)),
      bf2f((u16)(hv.w & 0xffffu)), bf2f((u16)(hv.w >> 16))};
    float nb[8] = {B0.x, B0.y, B0.z, B0.w, B1.x, B1.y, B1.z, B1.w};
    float na[8] = {A0.x, A0.y, A0.z, A0.w, A1.x, A1.y, A1.z, A1.w};
    short8 Aa, Ab;
#pragma unroll
    for (int jj = 0; jj < 8; ++jj) {
      float t = fmaf(hval[jj], nb[jj], na[jj]) * osc;
      u16 tb = f2bf(t);
      Aa[jj] = (short)(((wa >> jj) & 1u) ? tb : 0);
      Ab[jj] = (short)(((wb >> jj) & 1u) ? tb : 0);
    }
    short8 Bm = *(const short8*)(Wls + m * WLS + kof);          // W2 col m
    short8 Bl = *(const short8*)(Wls + (16 + m) * WLS + kof);   // W3 col m
    accM = __builtin_amdgcn_mfma_f32_16x16x32_bf16(Aa, Bm, accM, 0, 0, 0);
    accL = __builtin_amdgcn_mfma_f32_16x16x32_bf16(Ab, Bl, accL, 0, 0, 0);
  }
  // D: row = q*4+r, col = m
#pragma unroll
  for (int r = 0; r < 4; ++r) {
    long srow = (long)blockIdx.x * 64 + wv * 16 + q * 4 + r;
    if (srow < N_NODES) {
      XMLV[srow * 32 + m]      = f2bf(accM[r]);
      XMLV[srow * 32 + 16 + m] = f2bf(accL[r]);
    }
  }
}

// ---------------- final: aggregate interleaved mu|logvar + reparameterize ----------------
__global__ __launch_bounds__(256) void agg_final_k(
    const u16* __restrict__ XMLV, const int* __restrict__ row_ofs,
    const int* __restrict__ csr, const float* __restrict__ in_is,
    uint32_t ke0, uint32_t ke1, float* __restrict__ out) {
  int g = blockIdx.x * 4 + (threadIdx.x >> 6);  // exact: 25000*4 = N
  int lane = threadIdx.x & 63;
  int half = lane >> 5, c = lane & 31;
  int beg = row_ofs[g], end = row_ofs[g + 1];
  float s = 0.f;
  int j = beg + half;
  for (; j + 14 < end; j += 16) {
    int s0 = csr[j],      s1 = csr[j + 2],  s2 = csr[j + 4],  s3 = csr[j + 6];
    int s4 = csr[j + 8],  s5 = csr[j + 10], s6 = csr[j + 12], s7 = csr[j + 14];
    float v0 = bf2f(XMLV[(size_t)s0 * 32 + c]);
    float v1 = bf2f(XMLV[(size_t)s1 * 32 + c]);
    float v2 = bf2f(XMLV[(size_t)s2 * 32 + c]);
    float v3 = bf2f(XMLV[(size_t)s3 * 32 + c]);
    float v4 = bf2f(XMLV[(size_t)s4 * 32 + c]);
    float v5 = bf2f(XMLV[(size_t)s5 * 32 + c]);
    float v6 = bf2f(XMLV[(size_t)s6 * 32 + c]);
    float v7 = bf2f(XMLV[(size_t)s7 * 32 + c]);
    s += v0; s += v1; s += v2; s += v3;
    s += v4; s += v5; s += v6; s += v7;
  }
  for (; j + 6 < end; j += 8) {
    int s0 = csr[j], s1 = csr[j + 2], s2 = csr[j + 4], s3 = csr[j + 6];
    float v0 = bf2f(XMLV[(size_t)s0 * 32 + c]);
    float v1 = bf2f(XMLV[(size_t)s1 * 32 + c]);
    float v2 = bf2f(XMLV[(size_t)s2 * 32 + c]);
    float v3 = bf2f(XMLV[(size_t)s3 * 32 + c]);
    s += v0; s += v1; s += v2; s += v3;
  }
  for (; j < end; j += 2) s += bf2f(XMLV[(size_t)csr[j] * 32 + c]);
  s += __shfl(s, lane ^ 32, 64);
  if (half == 0) {
    s *= in_is[g];
    float other = __shfl(s, lane ^ 16, 64);  // mu lane c gets logvar from lane c+16
    if (c < 16) {
      uint32_t i = (uint32_t)(g * NCLS + c);
      uint32_t bits = tf_bits32(ke0, ke1, i);
      float f = __uint_as_float((bits >> 9) | 0x3f800000u) - 1.0f;
      const float lo = -0.99999994f;          // nextafter(-1,0)
      float u = fmaxf(lo, fmaf(f, 2.0f, lo)); // (hi-lo) rounds to exactly 2.0f
      float eps = 1.41421356f * erfinv_f32(u);
      out[i] = eps * expf(other) + s;
    }
  }
}

// ---------------- host ----------------
extern "C" void kernel_launch(void* const* d_in, const int* in_sizes, int n_in,
                              void* d_out, int out_size, void* d_ws, size_t ws_size,
                              hipStream_t stream) {
  (void)in_sizes; (void)n_in; (void)out_size; (void)ws_size;
  const float* x  = (const float*)d_in[0];
  const float* W1 = (const float*)d_in[1];
  const float* W2 = (const float*)d_in[2];
  const float* W3 = (const float*)d_in[3];
  const int* esrc = (const int*)d_in[4];
  const int* edst = (const int*)d_in[5];
  float* out = (float*)d_out;

  // subkeys of jax.random.split(jax.random.key(42), 4):
  // partitionable split -> key_i = FULL threefry output pair at counter (hi=0, lo=i)
  uint32_t kb[8];
  for (int j = 0; j < 4; ++j)
    threefry2x32(0u, 42u, 0u, (uint32_t)j, kb[2 * j], kb[2 * j + 1]);
  // k1=(kb0,kb1) drop-x; k2a=(kb2,kb3); k2b=(kb4,kb5); keps=(kb6,kb7)

  // workspace carve
  char* p = (char*)d_ws;
  auto take = [&](size_t bytes) -> void* {
    void* r = (void*)p;
    p += (bytes + 255) & ~(size_t)255;
    return r;
  };
  u16* Xb        = (u16*)take(sizeof(u16) * (size_t)N_NODES * IN_DIM);   // 102.4 MB
  u16* X1b       = (u16*)take(sizeof(u16) * (size_t)N_NODES * HID);
  u16* h1b       = (u16*)take(sizeof(u16) * (size_t)N_NODES * HID);
  u16* XMLV      = (u16*)take(sizeof(u16) * (size_t)N_NODES * 32);
  u16* W1t       = (u16*)take(sizeof(u16) * (size_t)IN_DIM * HID);
  u16* Wt23      = (u16*)take(sizeof(u16) * 32 * HID);
  uint32_t* mask2a = (uint32_t*)take((size_t)N_NODES * HID / 8);
  uint32_t* mask2b = (uint32_t*)take((size_t)N_NODES * HID / 8);
  int* in_deg    = (int*)take(sizeof(int) * N_NODES);
  float* out_is  = (float*)take(sizeof(float) * N_NODES);
  float* in_is   = (float*)take(sizeof(float) * N_NODES);
  int* row_ofs   = (int*)take(sizeof(int) * (N_NODES + 1));
  int* csr       = (int*)take(sizeof(int) * N_EDGES);
  float* bn      = (float*)take(sizeof(float) * 1024);

  // P16 partials [DBLK][N_NODES] u16 = 51.2 MB, aliased onto Xb (consumed before cast_x)
  u16* P16 = (u16*)Xb;

  hipMemsetAsync(bn, 0, sizeof(float) * 512, stream);

  hist_k<<<DBLK, 1024, 0, stream>>>(esrc, edst, P16);
  degsum_k<<<(N_NODES + 255) / 256, 256, 0, stream>>>(P16, in_deg, out_is, in_is);
  scan_offsets_k<<<1, 1024, 0, stream>>>(in_deg, row_ofs);
  place_k<<<DBLK, 1024, 0, stream>>>(esrc, edst, P16, row_ofs, csr);

  gen_mask_k<<<(N_NODES * HID) / 256, 256, 0, stream>>>(kb[2], kb[3], mask2a);
  gen_mask_k<<<(N_NODES * HID) / 256, 256, 0, stream>>>(kb[4], kb[5], mask2b);

  cast_w1_k<<<(IN_DIM * HID) / 256, 256, 0, stream>>>(W1, W1t);
  cast_w23_k<<<(32 * HID) / 256, 256, 0, stream>>>(W2, W3, Wt23);
  cast_x_k<<<(N_NODES * IN_DIM / 8) / 256, 256, 0, stream>>>(x, out_is, kb[0], kb[1], Xb);

  gemm1_k<<<(N_NODES + 63) / 64, 256, 0, stream>>>(Xb, W1t, X1b);
  agg_relu_k<<<(N_NODES / AG_RPB) * AG_G, 1024, 0, stream>>>(X1b, row_ofs, csr, in_is, h1b);
  bn_stats_k<<<512, 256, 0, stream>>>(h1b, bn);
  bn_fin_k<<<1, 256, 0, stream>>>(bn);
  gemm23_k<<<(N_NODES + 63) / 64, 256, 0, stream>>>(h1b, Wt23, mask2a, mask2b, out_is, bn, XMLV);
  agg_final_k<<<N_NODES / 4, 256, 0, stream>>>(XMLV, row_ofs, csr, in_is, kb[6], kb[7], out);
}

// Round 4
// 1033.885 us; speedup vs baseline: 1.5973x; 1.5973x over previous
//
#include <hip/hip_runtime.h>
#include <stdint.h>

#define N_NODES 100000
#define N_EDGES 3200000
#define IN_DIM  512
#define HID     256
#define NCLS    16

// graph-prep histogram geometry
#define DBLK   256                   // blocks (one per CU)
#define DCHUNK (N_EDGES / DBLK)      // 12500 edges per block
#define DWIN2  50000                 // nodes per LDS window in hist (byte counters, 100 KB)

typedef unsigned short u16;
typedef __attribute__((ext_vector_type(8))) short short8;
typedef __attribute__((ext_vector_type(4))) float float4v;

// ---------------- bf16 helpers ----------------
__device__ __forceinline__ float bf2f(u16 u) {
  return __uint_as_float(((uint32_t)u) << 16);
}
__device__ __forceinline__ u16 f2bf(float f) {   // round-to-nearest-even
  uint32_t u = __float_as_uint(f);
  return (u16)((u + 0x7fffu + ((u >> 16) & 1u)) >> 16);
}
__device__ __forceinline__ void acc8(float* a, uint4 v) {
  a[0] += bf2f((u16)(v.x & 0xffffu)); a[1] += bf2f((u16)(v.x >> 16));
  a[2] += bf2f((u16)(v.y & 0xffffu)); a[3] += bf2f((u16)(v.y >> 16));
  a[4] += bf2f((u16)(v.z & 0xffffu)); a[5] += bf2f((u16)(v.z >> 16));
  a[6] += bf2f((u16)(v.w & 0xffffu)); a[7] += bf2f((u16)(v.w >> 16));
}

// ---------------- Threefry-2x32 (exact JAX schedule, partitionable mode) ----------------
__host__ __device__ __forceinline__ uint32_t rotl32(uint32_t v, int d) {
  return (v << d) | (v >> (32 - d));
}

__host__ __device__ __forceinline__ void threefry2x32(uint32_t k0, uint32_t k1,
    uint32_t x0, uint32_t x1, uint32_t& o0, uint32_t& o1) {
  uint32_t ks0 = k0, ks1 = k1, ks2 = k0 ^ k1 ^ 0x1BD11BDAu;
  x0 += ks0; x1 += ks1;
#define TF_R(r) { x0 += x1; x1 = rotl32(x1, r); x1 ^= x0; }
  TF_R(13) TF_R(15) TF_R(26) TF_R(6)
  x0 += ks1; x1 += ks2 + 1u;
  TF_R(17) TF_R(29) TF_R(16) TF_R(24)
  x0 += ks2; x1 += ks0 + 2u;
  TF_R(13) TF_R(15) TF_R(26) TF_R(6)
  x0 += ks0; x1 += ks1 + 3u;
  TF_R(17) TF_R(29) TF_R(16) TF_R(24)
  x0 += ks1; x1 += ks2 + 4u;
  TF_R(13) TF_R(15) TF_R(26) TF_R(6)
  x0 += ks2; x1 += ks0 + 5u;
#undef TF_R
  o0 = x0; o1 = x1;
}

__host__ __device__ __forceinline__ uint32_t tf_bits32(uint32_t k0, uint32_t k1, uint32_t idx) {
  uint32_t o0, o1;
  threefry2x32(k0, k1, 0u, idx, o0, o1);
  return o0 ^ o1;
}

// ---------------- erfinv: XLA/Giles f32 polynomial ----------------
__device__ __forceinline__ float erfinv_f32(float x) {
  float w = -log1pf(-x * x);
  float p;
  if (w < 5.0f) {
    w -= 2.5f;
    p = 2.81022636e-08f;
    p = fmaf(p, w, 3.43273939e-07f);
    p = fmaf(p, w, -3.5233877e-06f);
    p = fmaf(p, w, -4.39150654e-06f);
    p = fmaf(p, w, 0.00021858087f);
    p = fmaf(p, w, -0.00125372503f);
    p = fmaf(p, w, -0.00417768164f);
    p = fmaf(p, w, 0.246640727f);
    p = fmaf(p, w, 1.50140941f);
  } else {
    w = sqrtf(w) - 3.0f;
    p = -0.000200214257f;
    p = fmaf(p, w, 0.000100950558f);
    p = fmaf(p, w, 0.00134934322f);
    p = fmaf(p, w, -0.00367342844f);
    p = fmaf(p, w, 0.00573950773f);
    p = fmaf(p, w, -0.0076224613f);
    p = fmaf(p, w, 0.00943887047f);
    p = fmaf(p, w, 1.00167406f);
    p = fmaf(p, w, 2.83297682f);
  }
  return p * x;
}

// ---------------- graph prep: privatized histogram, no global atomics ----------------
// P16[b][node] u16: lo8 = out-count, hi8 = in-count of block b's edge chunk.
// hist: 2 windows of 50000 nodes, byte-packed counters in u32 words
// (per-(block,node) counts are Poisson(0.125); max ~8 << 255, no cross-byte carry)
__global__ __launch_bounds__(1024) void hist_k(
    const int* __restrict__ esrc, const int* __restrict__ edst,
    u16* __restrict__ P16) {
  __shared__ uint32_t h32[DWIN2 / 2];   // 25000 u32 = 100 KB, 2 nodes per word
  const int b = blockIdx.x, tid = threadIdx.x;
  const int ebase = b * DCHUNK;
  for (int w = 0; w < 2; ++w) {
    const int lo = w * DWIN2;
    for (int i = tid; i < DWIN2 / 2; i += 1024) h32[i] = 0u;
    __syncthreads();
    for (int e = ebase + tid; e < ebase + DCHUNK; e += 1024) {
      int s = esrc[e], d = edst[e];
      unsigned su = (unsigned)(s - lo);
      if (su < (unsigned)DWIN2) atomicAdd(&h32[su >> 1], 1u << ((su & 1) * 16));
      unsigned du = (unsigned)(d - lo);
      if (du < (unsigned)DWIN2) atomicAdd(&h32[du >> 1], 0x100u << ((du & 1) * 16));
    }
    __syncthreads();
    for (int i = tid; i < DWIN2 / 2; i += 1024) {
      // word: [out_even | in_even<<8 | out_odd<<16 | in_odd<<24] == two P16 entries
      *(uint32_t*)(P16 + (size_t)b * N_NODES + lo + 2 * i) = h32[i];
    }
    __syncthreads();
  }
}

// column-sum partials -> degrees + inv-sqrt; rewrite P16[b][n] with exclusive in-prefix
__global__ void degsum_k(u16* __restrict__ P16, int* __restrict__ ind,
                         float* __restrict__ out_is, float* __restrict__ in_is) {
  int n = blockIdx.x * 256 + threadIdx.x;
  if (n >= N_NODES) return;
  uint32_t to = 0, ti = 0;
#pragma unroll 8
  for (int b = 0; b < DBLK; ++b) {
    uint32_t v = P16[(size_t)b * N_NODES + n];
    P16[(size_t)b * N_NODES + n] = (u16)ti;   // in-prefix: CSR slot base for (b, n)
    to += v & 0xffu; ti += v >> 8;
  }
  ind[n] = (int)ti;
  out_is[n] = rsqrtf(fmaxf((float)to, 1.0f));
  in_is[n]  = rsqrtf(fmaxf((float)ti, 1.0f));
}

// coalesced single-block tile scan: row_ofs = exclusive prefix of ind
__global__ __launch_bounds__(1024) void scan_offsets_k(
    const int* __restrict__ ind, int* __restrict__ row_ofs) {
  __shared__ int wsum[16];
  const int tid = threadIdx.x;
  const int lane = tid & 63, wv = tid >> 6;
  int running = 0;
  for (int base = 0; base < N_NODES; base += 1024) {
    const int i = base + tid;
    int v = (i < N_NODES) ? ind[i] : 0;
    int sc = v;
#pragma unroll
    for (int d = 1; d < 64; d <<= 1) {
      int t = __shfl_up(sc, d, 64);
      if (lane >= d) sc += t;
    }
    if (lane == 63) wsum[wv] = sc;
    __syncthreads();
    if (wv == 0) {
      int t = (lane < 16) ? wsum[lane] : 0;
#pragma unroll
      for (int d = 1; d < 16; d <<= 1) {
        int u = __shfl_up(t, d, 64);
        if (lane >= d) t += u;
      }
      if (lane < 16) wsum[lane] = t;   // inclusive scan of wave sums
    }
    __syncthreads();
    int wbase = (wv > 0) ? wsum[wv - 1] : 0;
    if (i < N_NODES) row_ofs[i] = running + wbase + sc - v;
    running += wsum[15];
    __syncthreads();   // protect wsum before next tile overwrites it
  }
  if (tid == 0) row_ofs[N_NODES] = running;
}

// atomic-free CSR placement, single window: u8-packed LDS cursors for all 100K nodes.
// slot = row_ofs[d] + P16[b][d] + per-block byte cursor (per-(block,node) count <= ~8)
__global__ __launch_bounds__(1024) void place_k(
    const int* __restrict__ esrc, const int* __restrict__ edst,
    const u16* __restrict__ P16, const int* __restrict__ row_ofs,
    int* __restrict__ csr) {
  __shared__ uint32_t cur32[N_NODES / 4];   // 25000 u32 = 100 KB, 4 nodes per word
  const int b = blockIdx.x, tid = threadIdx.x;
  for (int i = tid; i < N_NODES / 4; i += 1024) cur32[i] = 0u;
  __syncthreads();
  const int ebase = b * DCHUNK;
  for (int e = ebase + tid; e < ebase + DCHUNK; e += 1024) {
    int d = edst[e];
    int base = row_ofs[d] + (int)P16[(size_t)b * N_NODES + d];
    uint32_t old = atomicAdd(&cur32[d >> 2], 1u << ((d & 3) * 8));
    int c = (int)((old >> ((d & 3) * 8)) & 0xffu);
    csr[base + c] = esrc[e];
  }
}

// ---------------- dropout mask bits for hidden layer (both masks, 1 launch) ----------------
__global__ void gen_mask2_k(uint32_t ka0, uint32_t ka1, uint32_t kb0, uint32_t kb1,
                            uint32_t* __restrict__ maska, uint32_t* __restrict__ maskb) {
  uint32_t idx = blockIdx.x * blockDim.x + threadIdx.x;   // exact grid = size
  uint32_t ba = tf_bits32(ka0, ka1, idx);
  uint32_t bb = tf_bits32(kb0, kb1, idx);
  unsigned long long bala = __ballot((ba >> 31) == 0u);   // keep := u < 0.5
  unsigned long long balb = __ballot((bb >> 31) == 0u);
  if ((threadIdx.x & 63) == 0) {
    uint32_t w = idx >> 5;
    maska[w] = (uint32_t)bala;
    maska[w + 1] = (uint32_t)(bala >> 32);
    maskb[w] = (uint32_t)balb;
    maskb[w + 1] = (uint32_t)(balb >> 32);
  }
}

// ---------------- Xb = bf16(dropout1(x) * 2 * out_is) ----------------
__global__ __launch_bounds__(256) void cast_x_k(
    const float* __restrict__ x, const float* __restrict__ out_is,
    uint32_t k0, uint32_t k1, u16* __restrict__ Xb) {
  uint32_t t = blockIdx.x * 256u + threadIdx.x;   // 6.4M threads, 8 elems each
  uint32_t idx = t * 8u;
  uint32_t row = idx >> 9;
  float sc = 2.0f * out_is[row];
  float4 v0 = *(const float4*)(x + idx);
  float4 v1 = *(const float4*)(x + idx + 4);
  float vv[8] = {v0.x, v0.y, v0.z, v0.w, v1.x, v1.y, v1.z, v1.w};
  u16 o[8];
#pragma unroll
  for (int j = 0; j < 8; ++j) {
    uint32_t bits = tf_bits32(k0, k1, idx + (uint32_t)j);
    float val = (bits >> 31) ? 0.0f : vv[j] * sc;
    o[j] = f2bf(val);
  }
  uint4 pk;
  pk.x = (uint32_t)o[0] | ((uint32_t)o[1] << 16);
  pk.y = (uint32_t)o[2] | ((uint32_t)o[3] << 16);
  pk.z = (uint32_t)o[4] | ((uint32_t)o[5] << 16);
  pk.w = (uint32_t)o[6] | ((uint32_t)o[7] << 16);
  *(uint4*)(Xb + idx) = pk;
}

// ---------------- W1t = bf16(W1^T)  [256][512] ----------------
__global__ void cast_w1_k(const float* __restrict__ W1, u16* __restrict__ W1t) {
  int idx = blockIdx.x * blockDim.x + threadIdx.x;   // exact grid = 512*256
  int k = idx >> 8, n = idx & 255;
  W1t[n * IN_DIM + k] = f2bf(W1[idx]);
}

// ---------------- Wt23 = bf16([W2^T ; W3^T])  [32][256] ----------------
__global__ void cast_w23_k(const float* __restrict__ W2, const float* __restrict__ W3,
                           u16* __restrict__ Wt23) {
  int idx = blockIdx.x * blockDim.x + threadIdx.x;   // exact grid = 32*256
  int n = idx >> 8, k = idx & 255;
  float v = (n < 16) ? W2[k * NCLS + n] : W3[k * NCLS + (n - 16)];
  Wt23[n * HID + k] = f2bf(v);
}

// ---------------- GEMM1 (MFMA bf16): X1b = Xb @ W1  [100000,512]x[512,256] -> bf16 ----------------
#define LDA 40   // ushort stride (80 B: 16B-aligned rows, dword-stride 20 -> <=2-way bank alias)
__global__ __launch_bounds__(256) void gemm1_k(
    const u16* __restrict__ Xb, const u16* __restrict__ W1t, u16* __restrict__ X1b) {
  __shared__ u16 As[64 * LDA];    // [row][k0..31]
  __shared__ u16 Bs[256 * LDA];   // [n][k0..31]
  const int tid = threadIdx.x;
  const int w = tid >> 6, l = tid & 63;
  const int m16 = l & 15, q = l >> 4;
  const long base_row = (long)blockIdx.x * 64;

  float4v acc[4][4];
#pragma unroll
  for (int i = 0; i < 4; ++i)
#pragma unroll
    for (int j = 0; j < 4; ++j) acc[i][j] = (float4v)0.0f;

  const int arow = tid >> 2, ac = tid & 3;   // A staging: 64 rows x 4 chunks(8 bf16)
  const long agr = base_row + arow;

  for (int k0 = 0; k0 < IN_DIM; k0 += 32) {
    uint4 va = make_uint4(0, 0, 0, 0);
    if (agr < N_NODES) va = *(const uint4*)(Xb + agr * IN_DIM + k0 + ac * 8);
    *(uint4*)(As + arow * LDA + ac * 8) = va;
#pragma unroll
    for (int c = 0; c < 4; ++c) {   // B staging: n = tid, 32 bf16 per row (L2-resident W1t)
      uint4 vb = *(const uint4*)(W1t + (size_t)tid * IN_DIM + k0 + c * 8);
      *(uint4*)(Bs + tid * LDA + c * 8) = vb;
    }
    __syncthreads();
    short8 a[4], b[4];
#pragma unroll
    for (int rt = 0; rt < 4; ++rt)
      a[rt] = *(const short8*)(As + (rt * 16 + m16) * LDA + q * 8);
#pragma unroll
    for (int ct = 0; ct < 4; ++ct)
      b[ct] = *(const short8*)(Bs + ((w * 4 + ct) * 16 + m16) * LDA + q * 8);
#pragma unroll
    for (int rt = 0; rt < 4; ++rt)
#pragma unroll
      for (int ct = 0; ct < 4; ++ct)
        acc[rt][ct] = __builtin_amdgcn_mfma_f32_16x16x32_bf16(a[rt], b[ct], acc[rt][ct], 0, 0, 0);
    __syncthreads();
  }
#pragma unroll
  for (int rt = 0; rt < 4; ++rt) {
#pragma unroll
    for (int r = 0; r < 4; ++r) {
      long grow = base_row + rt * 16 + q * 4 + r;
      if (grow < N_NODES) {
#pragma unroll
        for (int ct = 0; ct < 4; ++ct)
          X1b[grow * HID + (w * 4 + ct) * 16 + m16] = f2bf(acc[rt][ct][r]);
      }
    }
  }
}

// ---------------- CSR gather-sum (bf16) + relu -> h1 bf16 ----------------
// 8-deep main loop + 4-deep + singles: keep >=8 row-gathers in flight per half-wave.
__global__ __launch_bounds__(256) void agg_relu_k(
    const u16* __restrict__ X1b, const int* __restrict__ row_ofs,
    const int* __restrict__ csr, const float* __restrict__ in_is,
    u16* __restrict__ h1b) {
  int d = blockIdx.x * 4 + (threadIdx.x >> 6);  // exact: 25000*4 = N
  int lane = threadIdx.x & 63;
  int half = lane >> 5;
  int col = (lane & 31) * 8;
  int beg = row_ofs[d], end = row_ofs[d + 1];
  float a[8];
#pragma unroll
  for (int i = 0; i < 8; ++i) a[i] = 0.0f;
  int j = beg + half;
  for (; j + 14 < end; j += 16) {
    int s0 = csr[j],      s1 = csr[j + 2],  s2 = csr[j + 4],  s3 = csr[j + 6];
    int s4 = csr[j + 8],  s5 = csr[j + 10], s6 = csr[j + 12], s7 = csr[j + 14];
    uint4 v0 = *(const uint4*)(X1b + (size_t)s0 * HID + col);
    uint4 v1 = *(const uint4*)(X1b + (size_t)s1 * HID + col);
    uint4 v2 = *(const uint4*)(X1b + (size_t)s2 * HID + col);
    uint4 v3 = *(const uint4*)(X1b + (size_t)s3 * HID + col);
    uint4 v4 = *(const uint4*)(X1b + (size_t)s4 * HID + col);
    uint4 v5 = *(const uint4*)(X1b + (size_t)s5 * HID + col);
    uint4 v6 = *(const uint4*)(X1b + (size_t)s6 * HID + col);
    uint4 v7 = *(const uint4*)(X1b + (size_t)s7 * HID + col);
    acc8(a, v0); acc8(a, v1); acc8(a, v2); acc8(a, v3);
    acc8(a, v4); acc8(a, v5); acc8(a, v6); acc8(a, v7);
  }
  for (; j + 6 < end; j += 8) {
    int s0 = csr[j], s1 = csr[j + 2], s2 = csr[j + 4], s3 = csr[j + 6];
    uint4 v0 = *(const uint4*)(X1b + (size_t)s0 * HID + col);
    uint4 v1 = *(const uint4*)(X1b + (size_t)s1 * HID + col);
    uint4 v2 = *(const uint4*)(X1b + (size_t)s2 * HID + col);
    uint4 v3 = *(const uint4*)(X1b + (size_t)s3 * HID + col);
    acc8(a, v0); acc8(a, v1); acc8(a, v2); acc8(a, v3);
  }
  for (; j < end; j += 2) {
    uint4 v0 = *(const uint4*)(X1b + (size_t)csr[j] * HID + col);
    acc8(a, v0);
  }
#pragma unroll
  for (int i = 0; i < 8; ++i) a[i] += __shfl(a[i], lane ^ 32, 64);
  if (half == 0) {
    float is = in_is[d];
    u16 o[8];
#pragma unroll
    for (int i = 0; i < 8; ++i) o[i] = f2bf(fmaxf(a[i] * is, 0.0f));
    uint4 pk;
    pk.x = (uint32_t)o[0] | ((uint32_t)o[1] << 16);
    pk.y = (uint32_t)o[2] | ((uint32_t)o[3] << 16);
    pk.z = (uint32_t)o[4] | ((uint32_t)o[5] << 16);
    pk.w = (uint32_t)o[6] | ((uint32_t)o[7] << 16);
    *(uint4*)(h1b + (size_t)d * HID + col) = pk;
  }
}

// ---------------- BatchNorm stats (bf16 in, fp32 accumulate), vectorized ----------------
// 256 blocks; row r = blockIdx + 256*m; m = (tid>>5) + 8*k. Each half-wave reads a
// coalesced 512 B row slice (uint4/lane). LDS reduce -> 512 global atomics per block.
__global__ __launch_bounds__(256) void bn_stats_k(const u16* __restrict__ h1b,
                                                  float* __restrict__ bn) {
  __shared__ float ls[512];
  const int tid = threadIdx.x;
  const int cb = (tid & 31) * 8;   // col base
  const int ms = tid >> 5;         // row-stream 0..7
  float s[8], s2[8];
#pragma unroll
  for (int i = 0; i < 8; ++i) { s[i] = 0.f; s2[i] = 0.f; }
  for (int m = ms;; m += 8) {
    int r = blockIdx.x + 256 * m;
    if (r >= N_NODES) break;
    uint4 v = *(const uint4*)(h1b + (size_t)r * HID + cb);
    float f[8];
    f[0] = bf2f((u16)(v.x & 0xffffu)); f[1] = bf2f((u16)(v.x >> 16));
    f[2] = bf2f((u16)(v.y & 0xffffu)); f[3] = bf2f((u16)(v.y >> 16));
    f[4] = bf2f((u16)(v.z & 0xffffu)); f[5] = bf2f((u16)(v.z >> 16));
    f[6] = bf2f((u16)(v.w & 0xffffu)); f[7] = bf2f((u16)(v.w >> 16));
#pragma unroll
    for (int i = 0; i < 8; ++i) { s[i] += f[i]; s2[i] += f[i] * f[i]; }
  }
  ls[tid] = 0.f; ls[tid + 256] = 0.f;
  __syncthreads();
#pragma unroll
  for (int i = 0; i < 8; ++i) {
    atomicAdd(&ls[cb + i], s[i]);
    atomicAdd(&ls[256 + cb + i], s2[i]);
  }
  __syncthreads();
  atomicAdd(&bn[tid], ls[tid]);
  atomicAdd(&bn[HID + tid], ls[256 + tid]);
}

__global__ void bn_fin_k(float* __restrict__ bn) {
  int c = threadIdx.x;
  float mean = bn[c] / (float)N_NODES;
  float var = bn[HID + c] / (float)N_NODES - mean * mean;
  float istd = rsqrtf(var + 1e-5f);
  bn[512 + c] = istd;           // cB
  bn[768 + c] = -mean * istd;   // cA:  normalized = h*cB + cA
}

// ---------------- GEMM2/3 (MFMA): XMLV[row] = [mu(16) | logvar(16)] bf16 ----------------
#define WLS 264   // u16 row stride for Wls: dword-stride 132 -> 2-way bank alias (free)
__global__ __launch_bounds__(256) void gemm23_k(
    const u16* __restrict__ h1b, const u16* __restrict__ Wt23,
    const uint32_t* __restrict__ mask2a, const uint32_t* __restrict__ mask2b,
    const float* __restrict__ out_is, const float* __restrict__ bn,
    u16* __restrict__ XMLV) {
  __shared__ u16 Wls[32 * WLS];
  __shared__ float cB[HID], cA[HID];
  const int tid = threadIdx.x;
#pragma unroll
  for (int i = 0; i < 4; ++i) {   // stage Wt23 (16KB) into padded LDS
    int idx = tid + i * 256;      // 1024 uint4 chunks
    int n = idx >> 5, c = idx & 31;
    *(uint4*)(Wls + n * WLS + c * 8) = ((const uint4*)Wt23)[idx];
  }
  cB[tid] = bn[512 + tid];
  cA[tid] = bn[768 + tid];
  __syncthreads();

  const int wv = tid >> 6, lane = tid & 63;
  const int m = lane & 15, q = lane >> 4;
  const long arow = (long)blockIdx.x * 64 + wv * 16 + m;   // A row this lane loads
  const bool valid = arow < N_NODES;
  const float osc = valid ? 2.0f * out_is[arow] : 0.0f;

  float4v accM = (float4v)0.0f, accL = (float4v)0.0f;
  for (int kc = 0; kc < HID; kc += 32) {
    const int kof = kc + q * 8;
    uint4 hv = make_uint4(0, 0, 0, 0);
    uint32_t wa = 0, wb = 0;
    if (valid) {
      hv = *(const uint4*)(h1b + arow * HID + kof);
      uint32_t widx = ((uint32_t)arow * HID + (uint32_t)kc) >> 5;
      wa = mask2a[widx] >> (q * 8);
      wb = mask2b[widx] >> (q * 8);
    }
    float4 B0 = *(const float4*)(cB + kof);
    float4 B1 = *(const float4*)(cB + kof + 4);
    float4 A0 = *(const float4*)(cA + kof);
    float4 A1 = *(const float4*)(cA + kof + 4);
    float hval[8] = {
      bf2f((u16)(hv.x & 0xffffu)), bf2f((u16)(hv.x >> 16)),
      bf2f((u16)(hv.y & 0xffffu)), bf2f((u16)(hv.y >> 16)),
      bf2f((u16)(hv.z & 0xffffu)), bf2f((u16)(hv.z >> 16)),
      bf2f((u16)(hv.w & 0xffffu)), bf2f((u16)(hv.w >> 16))};
    float nb[8] = {B0.x, B0.y, B0.z, B0.w, B1.x, B1.y, B1.z, B1.w};
    float na[8] = {A0.x, A0.y, A0.z, A0.w, A1.x, A1.y, A1.z, A1.w};
    short8 Aa, Ab;
#pragma unroll
    for (int jj = 0; jj < 8; ++jj) {
      float t = fmaf(hval[jj], nb[jj], na[jj]) * osc;
      u16 tb = f2bf(t);
      Aa[jj] = (short)(((wa >> jj) & 1u) ? tb : 0);
      Ab[jj] = (short)(((wb >> jj) & 1u) ? tb : 0);
    }
    short8 Bm = *(const short8*)(Wls + m * WLS + kof);          // W2 col m
    short8 Bl = *(const short8*)(Wls + (16 + m) * WLS + kof);   // W3 col m
    accM = __builtin_amdgcn_mfma_f32_16x16x32_bf16(Aa, Bm, accM, 0, 0, 0);
    accL = __builtin_amdgcn_mfma_f32_16x16x32_bf16(Ab, Bl, accL, 0, 0, 0);
  }
  // D: row = q*4+r, col = m
#pragma unroll
  for (int r = 0; r < 4; ++r) {
    long srow = (long)blockIdx.x * 64 + wv * 16 + q * 4 + r;
    if (srow < N_NODES) {
      XMLV[srow * 32 + m]      = f2bf(accM[r]);
      XMLV[srow * 32 + 16 + m] = f2bf(accL[r]);
    }
  }
}

// ---------------- final: aggregate interleaved mu|logvar + reparameterize ----------------
__global__ __launch_bounds__(256) void agg_final_k(
    const u16* __restrict__ XMLV, const int* __restrict__ row_ofs,
    const int* __restrict__ csr, const float* __restrict__ in_is,
    uint32_t ke0, uint32_t ke1, float* __restrict__ out) {
  int g = blockIdx.x * 4 + (threadIdx.x >> 6);  // exact: 25000*4 = N
  int lane = threadIdx.x & 63;
  int half = lane >> 5, c = lane & 31;
  int beg = row_ofs[g], end = row_ofs[g + 1];
  float s = 0.f;
  int j = beg + half;
  for (; j + 14 < end; j += 16) {
    int s0 = csr[j],      s1 = csr[j + 2],  s2 = csr[j + 4],  s3 = csr[j + 6];
    int s4 = csr[j + 8],  s5 = csr[j + 10], s6 = csr[j + 12], s7 = csr[j + 14];
    float v0 = bf2f(XMLV[(size_t)s0 * 32 + c]);
    float v1 = bf2f(XMLV[(size_t)s1 * 32 + c]);
    float v2 = bf2f(XMLV[(size_t)s2 * 32 + c]);
    float v3 = bf2f(XMLV[(size_t)s3 * 32 + c]);
    float v4 = bf2f(XMLV[(size_t)s4 * 32 + c]);
    float v5 = bf2f(XMLV[(size_t)s5 * 32 + c]);
    float v6 = bf2f(XMLV[(size_t)s6 * 32 + c]);
    float v7 = bf2f(XMLV[(size_t)s7 * 32 + c]);
    s += v0; s += v1; s += v2; s += v3;
    s += v4; s += v5; s += v6; s += v7;
  }
  for (; j + 6 < end; j += 8) {
    int s0 = csr[j], s1 = csr[j + 2], s2 = csr[j + 4], s3 = csr[j + 6];
    float v0 = bf2f(XMLV[(size_t)s0 * 32 + c]);
    float v1 = bf2f(XMLV[(size_t)s1 * 32 + c]);
    float v2 = bf2f(XMLV[(size_t)s2 * 32 + c]);
    float v3 = bf2f(XMLV[(size_t)s3 * 32 + c]);
    s += v0; s += v1; s += v2; s += v3;
  }
  for (; j < end; j += 2) s += bf2f(XMLV[(size_t)csr[j] * 32 + c]);
  s += __shfl(s, lane ^ 32, 64);
  if (half == 0) {
    s *= in_is[g];
    float other = __shfl(s, lane ^ 16, 64);  // mu lane c gets logvar from lane c+16
    if (c < 16) {
      uint32_t i = (uint32_t)(g * NCLS + c);
      uint32_t bits = tf_bits32(ke0, ke1, i);
      float f = __uint_as_float((bits >> 9) | 0x3f800000u) - 1.0f;
      const float lo = -0.99999994f;          // nextafter(-1,0)
      float u = fmaxf(lo, fmaf(f, 2.0f, lo)); // (hi-lo) rounds to exactly 2.0f
      float eps = 1.41421356f * erfinv_f32(u);
      out[i] = eps * expf(other) + s;
    }
  }
}

// ---------------- host ----------------
extern "C" void kernel_launch(void* const* d_in, const int* in_sizes, int n_in,
                              void* d_out, int out_size, void* d_ws, size_t ws_size,
                              hipStream_t stream) {
  (void)in_sizes; (void)n_in; (void)out_size; (void)ws_size;
  const float* x  = (const float*)d_in[0];
  const float* W1 = (const float*)d_in[1];
  const float* W2 = (const float*)d_in[2];
  const float* W3 = (const float*)d_in[3];
  const int* esrc = (const int*)d_in[4];
  const int* edst = (const int*)d_in[5];
  float* out = (float*)d_out;

  // subkeys of jax.random.split(jax.random.key(42), 4):
  // partitionable split -> key_i = FULL threefry output pair at counter (hi=0, lo=i)
  uint32_t kb[8];
  for (int j = 0; j < 4; ++j)
    threefry2x32(0u, 42u, 0u, (uint32_t)j, kb[2 * j], kb[2 * j + 1]);
  // k1=(kb0,kb1) drop-x; k2a=(kb2,kb3); k2b=(kb4,kb5); keps=(kb6,kb7)

  // workspace carve
  char* p = (char*)d_ws;
  auto take = [&](size_t bytes) -> void* {
    void* r = (void*)p;
    p += (bytes + 255) & ~(size_t)255;
    return r;
  };
  u16* Xb        = (u16*)take(sizeof(u16) * (size_t)N_NODES * IN_DIM);   // 102.4 MB
  u16* X1b       = (u16*)take(sizeof(u16) * (size_t)N_NODES * HID);
  u16* h1b       = (u16*)take(sizeof(u16) * (size_t)N_NODES * HID);
  u16* XMLV      = (u16*)take(sizeof(u16) * (size_t)N_NODES * 32);
  u16* W1t       = (u16*)take(sizeof(u16) * (size_t)IN_DIM * HID);
  u16* Wt23      = (u16*)take(sizeof(u16) * 32 * HID);
  uint32_t* mask2a = (uint32_t*)take((size_t)N_NODES * HID / 8);
  uint32_t* mask2b = (uint32_t*)take((size_t)N_NODES * HID / 8);
  int* in_deg    = (int*)take(sizeof(int) * N_NODES);
  float* out_is  = (float*)take(sizeof(float) * N_NODES);
  float* in_is   = (float*)take(sizeof(float) * N_NODES);
  int* row_ofs   = (int*)take(sizeof(int) * (N_NODES + 1));
  int* csr       = (int*)take(sizeof(int) * N_EDGES);
  float* bn      = (float*)take(sizeof(float) * 1024);

  // P16 partials [DBLK][N_NODES] u16 = 51.2 MB, aliased onto Xb (consumed before cast_x)
  u16* P16 = (u16*)Xb;

  hipMemsetAsync(bn, 0, sizeof(float) * 512, stream);

  hist_k<<<DBLK, 1024, 0, stream>>>(esrc, edst, P16);
  degsum_k<<<(N_NODES + 255) / 256, 256, 0, stream>>>(P16, in_deg, out_is, in_is);
  scan_offsets_k<<<1, 1024, 0, stream>>>(in_deg, row_ofs);
  place_k<<<DBLK, 1024, 0, stream>>>(esrc, edst, P16, row_ofs, csr);

  gen_mask2_k<<<(N_NODES * HID) / 256, 256, 0, stream>>>(kb[2], kb[3], kb[4], kb[5],
                                                         mask2a, mask2b);

  cast_w1_k<<<(IN_DIM * HID) / 256, 256, 0, stream>>>(W1, W1t);
  cast_w23_k<<<(32 * HID) / 256, 256, 0, stream>>>(W2, W3, Wt23);
  cast_x_k<<<(N_NODES * IN_DIM / 8) / 256, 256, 0, stream>>>(x, out_is, kb[0], kb[1], Xb);

  gemm1_k<<<(N_NODES + 63) / 64, 256, 0, stream>>>(Xb, W1t, X1b);
  agg_relu_k<<<N_NODES / 4, 256, 0, stream>>>(X1b, row_ofs, csr, in_is, h1b);
  bn_stats_k<<<256, 256, 0, stream>>>(h1b, bn);
  bn_fin_k<<<1, 256, 0, stream>>>(bn);
  gemm23_k<<<(N_NODES + 63) / 64, 256, 0, stream>>>(h1b, Wt23, mask2a, mask2b, out_is, bn, XMLV);
  agg_final_k<<<N_NODES / 4, 256, 0, stream>>>(XMLV, row_ofs, csr, in_is, kb[6], kb[7], out);
}

// Round 5
// 1014.754 us; speedup vs baseline: 1.6274x; 1.0189x over previous
//
#include <hip/hip_runtime.h>
#include <stdint.h>

#define N_NODES 100000
#define N_EDGES 3200000
#define IN_DIM  512
#define HID     256
#define NCLS    16

// graph-prep histogram geometry
#define DBLK   256                   // blocks (one per CU)
#define DCHUNK (N_EDGES / DBLK)      // 12500 edges per block
#define DWIN2  50000                 // nodes per LDS window in hist (byte counters, 100 KB)

typedef unsigned short u16;
typedef __attribute__((ext_vector_type(8))) short short8;
typedef __attribute__((ext_vector_type(4))) float float4v;

// ---------------- bf16 helpers ----------------
__device__ __forceinline__ float bf2f(u16 u) {
  return __uint_as_float(((uint32_t)u) << 16);
}
__device__ __forceinline__ u16 f2bf(float f) {   // round-to-nearest-even
  uint32_t u = __float_as_uint(f);
  return (u16)((u + 0x7fffu + ((u >> 16) & 1u)) >> 16);
}
__device__ __forceinline__ void acc8(float* a, uint4 v) {
  a[0] += bf2f((u16)(v.x & 0xffffu)); a[1] += bf2f((u16)(v.x >> 16));
  a[2] += bf2f((u16)(v.y & 0xffffu)); a[3] += bf2f((u16)(v.y >> 16));
  a[4] += bf2f((u16)(v.z & 0xffffu)); a[5] += bf2f((u16)(v.z >> 16));
  a[6] += bf2f((u16)(v.w & 0xffffu)); a[7] += bf2f((u16)(v.w >> 16));
}

// async global->LDS, 16B per lane: LDS dest = wave-uniform base + lane*16
__device__ __forceinline__ void gload16(const void* g, void* l) {
  __builtin_amdgcn_global_load_lds(
      (const __attribute__((address_space(1))) uint32_t*)g,
      (__attribute__((address_space(3))) uint32_t*)l, 16, 0, 0);
}

// ---------------- Threefry-2x32 (exact JAX schedule, partitionable mode) ----------------
__host__ __device__ __forceinline__ uint32_t rotl32(uint32_t v, int d) {
  return (v << d) | (v >> (32 - d));
}

__host__ __device__ __forceinline__ void threefry2x32(uint32_t k0, uint32_t k1,
    uint32_t x0, uint32_t x1, uint32_t& o0, uint32_t& o1) {
  uint32_t ks0 = k0, ks1 = k1, ks2 = k0 ^ k1 ^ 0x1BD11BDAu;
  x0 += ks0; x1 += ks1;
#define TF_R(r) { x0 += x1; x1 = rotl32(x1, r); x1 ^= x0; }
  TF_R(13) TF_R(15) TF_R(26) TF_R(6)
  x0 += ks1; x1 += ks2 + 1u;
  TF_R(17) TF_R(29) TF_R(16) TF_R(24)
  x0 += ks2; x1 += ks0 + 2u;
  TF_R(13) TF_R(15) TF_R(26) TF_R(6)
  x0 += ks0; x1 += ks1 + 3u;
  TF_R(17) TF_R(29) TF_R(16) TF_R(24)
  x0 += ks1; x1 += ks2 + 4u;
  TF_R(13) TF_R(15) TF_R(26) TF_R(6)
  x0 += ks2; x1 += ks0 + 5u;
#undef TF_R
  o0 = x0; o1 = x1;
}

__host__ __device__ __forceinline__ uint32_t tf_bits32(uint32_t k0, uint32_t k1, uint32_t idx) {
  uint32_t o0, o1;
  threefry2x32(k0, k1, 0u, idx, o0, o1);
  return o0 ^ o1;
}

// ---------------- erfinv: XLA/Giles f32 polynomial ----------------
__device__ __forceinline__ float erfinv_f32(float x) {
  float w = -log1pf(-x * x);
  float p;
  if (w < 5.0f) {
    w -= 2.5f;
    p = 2.81022636e-08f;
    p = fmaf(p, w, 3.43273939e-07f);
    p = fmaf(p, w, -3.5233877e-06f);
    p = fmaf(p, w, -4.39150654e-06f);
    p = fmaf(p, w, 0.00021858087f);
    p = fmaf(p, w, -0.00125372503f);
    p = fmaf(p, w, -0.00417768164f);
    p = fmaf(p, w, 0.246640727f);
    p = fmaf(p, w, 1.50140941f);
  } else {
    w = sqrtf(w) - 3.0f;
    p = -0.000200214257f;
    p = fmaf(p, w, 0.000100950558f);
    p = fmaf(p, w, 0.00134934322f);
    p = fmaf(p, w, -0.00367342844f);
    p = fmaf(p, w, 0.00573950773f);
    p = fmaf(p, w, -0.0076224613f);
    p = fmaf(p, w, 0.00943887047f);
    p = fmaf(p, w, 1.00167406f);
    p = fmaf(p, w, 2.83297682f);
  }
  return p * x;
}

// ---------------- graph prep: privatized histogram, no global atomics ----------------
__global__ __launch_bounds__(1024) void hist_k(
    const int* __restrict__ esrc, const int* __restrict__ edst,
    u16* __restrict__ P16) {
  __shared__ uint32_t h32[DWIN2 / 2];   // 25000 u32 = 100 KB, 2 nodes per word
  const int b = blockIdx.x, tid = threadIdx.x;
  const int ebase = b * DCHUNK;
  for (int w = 0; w < 2; ++w) {
    const int lo = w * DWIN2;
    for (int i = tid; i < DWIN2 / 2; i += 1024) h32[i] = 0u;
    __syncthreads();
    for (int e = ebase + tid; e < ebase + DCHUNK; e += 1024) {
      int s = esrc[e], d = edst[e];
      unsigned su = (unsigned)(s - lo);
      if (su < (unsigned)DWIN2) atomicAdd(&h32[su >> 1], 1u << ((su & 1) * 16));
      unsigned du = (unsigned)(d - lo);
      if (du < (unsigned)DWIN2) atomicAdd(&h32[du >> 1], 0x100u << ((du & 1) * 16));
    }
    __syncthreads();
    for (int i = tid; i < DWIN2 / 2; i += 1024) {
      *(uint32_t*)(P16 + (size_t)b * N_NODES + lo + 2 * i) = h32[i];
    }
    __syncthreads();
  }
}

// column-sum partials -> degrees + inv-sqrt; rewrite P16[b][n] with exclusive in-prefix
__global__ void degsum_k(u16* __restrict__ P16, int* __restrict__ ind,
                         float* __restrict__ out_is, float* __restrict__ in_is) {
  int n = blockIdx.x * 256 + threadIdx.x;
  if (n >= N_NODES) return;
  uint32_t to = 0, ti = 0;
#pragma unroll 8
  for (int b = 0; b < DBLK; ++b) {
    uint32_t v = P16[(size_t)b * N_NODES + n];
    P16[(size_t)b * N_NODES + n] = (u16)ti;   // in-prefix: CSR slot base for (b, n)
    to += v & 0xffu; ti += v >> 8;
  }
  ind[n] = (int)ti;
  out_is[n] = rsqrtf(fmaxf((float)to, 1.0f));
  in_is[n]  = rsqrtf(fmaxf((float)ti, 1.0f));
}

// coalesced single-block tile scan: row_ofs = exclusive prefix of ind
__global__ __launch_bounds__(1024) void scan_offsets_k(
    const int* __restrict__ ind, int* __restrict__ row_ofs) {
  __shared__ int wsum[16];
  const int tid = threadIdx.x;
  const int lane = tid & 63, wv = tid >> 6;
  int running = 0;
  for (int base = 0; base < N_NODES; base += 1024) {
    const int i = base + tid;
    int v = (i < N_NODES) ? ind[i] : 0;
    int sc = v;
#pragma unroll
    for (int d = 1; d < 64; d <<= 1) {
      int t = __shfl_up(sc, d, 64);
      if (lane >= d) sc += t;
    }
    if (lane == 63) wsum[wv] = sc;
    __syncthreads();
    if (wv == 0) {
      int t = (lane < 16) ? wsum[lane] : 0;
#pragma unroll
      for (int d = 1; d < 16; d <<= 1) {
        int u = __shfl_up(t, d, 64);
        if (lane >= d) t += u;
      }
      if (lane < 16) wsum[lane] = t;   // inclusive scan of wave sums
    }
    __syncthreads();
    int wbase = (wv > 0) ? wsum[wv - 1] : 0;
    if (i < N_NODES) row_ofs[i] = running + wbase + sc - v;
    running += wsum[15];
    __syncthreads();   // protect wsum before next tile overwrites it
  }
  if (tid == 0) row_ofs[N_NODES] = running;
}

// atomic-free CSR placement, single window: u8-packed LDS cursors for all 100K nodes.
__global__ __launch_bounds__(1024) void place_k(
    const int* __restrict__ esrc, const int* __restrict__ edst,
    const u16* __restrict__ P16, const int* __restrict__ row_ofs,
    int* __restrict__ csr) {
  __shared__ uint32_t cur32[N_NODES / 4];   // 25000 u32 = 100 KB, 4 nodes per word
  const int b = blockIdx.x, tid = threadIdx.x;
  for (int i = tid; i < N_NODES / 4; i += 1024) cur32[i] = 0u;
  __syncthreads();
  const int ebase = b * DCHUNK;
  for (int e = ebase + tid; e < ebase + DCHUNK; e += 1024) {
    int d = edst[e];
    int base = row_ofs[d] + (int)P16[(size_t)b * N_NODES + d];
    uint32_t old = atomicAdd(&cur32[d >> 2], 1u << ((d & 3) * 8));
    int c = (int)((old >> ((d & 3) * 8)) & 0xffu);
    csr[base + c] = esrc[e];
  }
}

// ---------------- dropout mask bits for hidden layer (both masks, 1 launch) ----------------
__global__ void gen_mask2_k(uint32_t ka0, uint32_t ka1, uint32_t kb0, uint32_t kb1,
                            uint32_t* __restrict__ maska, uint32_t* __restrict__ maskb) {
  uint32_t idx = blockIdx.x * blockDim.x + threadIdx.x;   // exact grid = size
  uint32_t ba = tf_bits32(ka0, ka1, idx);
  uint32_t bb = tf_bits32(kb0, kb1, idx);
  unsigned long long bala = __ballot((ba >> 31) == 0u);   // keep := u < 0.5
  unsigned long long balb = __ballot((bb >> 31) == 0u);
  if ((threadIdx.x & 63) == 0) {
    uint32_t w = idx >> 5;
    maska[w] = (uint32_t)bala;
    maska[w + 1] = (uint32_t)(bala >> 32);
    maskb[w] = (uint32_t)balb;
    maskb[w + 1] = (uint32_t)(balb >> 32);
  }
}

// ---------------- Xb = bf16(dropout1(x) * 2 * out_is) ----------------
__global__ __launch_bounds__(256) void cast_x_k(
    const float* __restrict__ x, const float* __restrict__ out_is,
    uint32_t k0, uint32_t k1, u16* __restrict__ Xb) {
  uint32_t t = blockIdx.x * 256u + threadIdx.x;   // 6.4M threads, 8 elems each
  uint32_t idx = t * 8u;
  uint32_t row = idx >> 9;
  float sc = 2.0f * out_is[row];
  float4 v0 = *(const float4*)(x + idx);
  float4 v1 = *(const float4*)(x + idx + 4);
  float vv[8] = {v0.x, v0.y, v0.z, v0.w, v1.x, v1.y, v1.z, v1.w};
  u16 o[8];
#pragma unroll
  for (int j = 0; j < 8; ++j) {
    uint32_t bits = tf_bits32(k0, k1, idx + (uint32_t)j);
    float val = (bits >> 31) ? 0.0f : vv[j] * sc;
    o[j] = f2bf(val);
  }
  uint4 pk;
  pk.x = (uint32_t)o[0] | ((uint32_t)o[1] << 16);
  pk.y = (uint32_t)o[2] | ((uint32_t)o[3] << 16);
  pk.z = (uint32_t)o[4] | ((uint32_t)o[5] << 16);
  pk.w = (uint32_t)o[6] | ((uint32_t)o[7] << 16);
  *(uint4*)(Xb + idx) = pk;
}

// ---------------- W1t + Wt23 cast, single launch ----------------
__global__ void cast_w_k(const float* __restrict__ W1, const float* __restrict__ W2,
                         const float* __restrict__ W3, u16* __restrict__ W1t,
                         u16* __restrict__ Wt23) {
  int idx = blockIdx.x * blockDim.x + threadIdx.x;   // grid = (512*256 + 32*256)/256
  if (idx < IN_DIM * HID) {
    int k = idx >> 8, n = idx & 255;
    W1t[n * IN_DIM + k] = f2bf(W1[idx]);
  } else {
    int t = idx - IN_DIM * HID;
    int n = t >> 8, k = t & 255;
    float v = (n < 16) ? W2[k * NCLS + n] : W3[k * NCLS + (n - 16)];
    Wt23[n * HID + k] = f2bf(v);
  }
}

// ---------------- GEMM1 v2 (MFMA bf16): X1b = Xb @ W1 ----------------
// 128x256 block, 8 waves (2x4 of 64x64), BK=64, global_load_lds(16B) staging,
// XOR-chunk swizzle (chunk ^= row&7) applied on global source AND ds_read so
// ds_read_b128 start offsets cover all 8 bank positions (linear would be 16-way).
#define G1_BM 128
#define G1_BKC 8   // chunks of 8 u16 (16 B) per row; BK = 64
__global__ __launch_bounds__(512, 2) void gemm1_k(
    const u16* __restrict__ Xb, const u16* __restrict__ W1t, u16* __restrict__ X1b) {
  __shared__ u16 As[G1_BM * 64];    // [row][chunk] 16 KB, swizzled chunks
  __shared__ u16 Bs[256 * 64];      // 32 KB
  const int tid = threadIdx.x;
  const int wid = tid >> 6, lane = tid & 63;
  const int wr = wid >> 2, wc = wid & 3;     // wave tile: rows wr*64.., cols wc*64..
  const int m16 = lane & 15, q = lane >> 4;
  const int srow = lane >> 3, schunk = lane & 7;   // staging: 8 rows x 8 chunks per issue
  const long base_row = (long)blockIdx.x * G1_BM;

  float4v acc[4][4];
#pragma unroll
  for (int i = 0; i < 4; ++i)
#pragma unroll
    for (int j = 0; j < 4; ++j) acc[i][j] = (float4v)0.0f;

  for (int ks = 0; ks < IN_DIM / 64; ++ks) {
    // A: 16 KB = 16 issues; wave wid does j = wid*2+i, rows j*8..j*8+8
#pragma unroll
    for (int i = 0; i < 2; ++i) {
      int j = wid * 2 + i;
      int row = j * 8 + srow;
      int gch = ks * G1_BKC + (schunk ^ (row & 7));
      // OOB rows read adjacent workspace (safe); outputs guarded on store
      gload16(Xb + (base_row + row) * IN_DIM + gch * 8, As + j * 512);
    }
    // B: 32 KB = 32 issues; j = wid*4+i, cols j*8..j*8+8
#pragma unroll
    for (int i = 0; i < 4; ++i) {
      int j = wid * 4 + i;
      int n = j * 8 + srow;
      int gch = ks * G1_BKC + (schunk ^ (n & 7));
      gload16(W1t + (size_t)n * IN_DIM + gch * 8, Bs + j * 512);
    }
    __syncthreads();   // drains vmcnt before barrier
#pragma unroll
    for (int kk = 0; kk < 2; ++kk) {
      short8 a[4], b[4];
      const int kq = kk * 4 + q;
      const int c = kq ^ (m16 & 7);   // row&7 == m16&7 (row bases are x16)
#pragma unroll
      for (int rt = 0; rt < 4; ++rt) {
        int row = wr * 64 + rt * 16 + m16;
        a[rt] = *(const short8*)(As + row * 64 + c * 8);
      }
#pragma unroll
      for (int ct = 0; ct < 4; ++ct) {
        int n = wc * 64 + ct * 16 + m16;
        b[ct] = *(const short8*)(Bs + n * 64 + c * 8);
      }
#pragma unroll
      for (int rt = 0; rt < 4; ++rt)
#pragma unroll
        for (int ct = 0; ct < 4; ++ct)
          acc[rt][ct] = __builtin_amdgcn_mfma_f32_16x16x32_bf16(a[rt], b[ct], acc[rt][ct], 0, 0, 0);
    }
    __syncthreads();
  }
#pragma unroll
  for (int rt = 0; rt < 4; ++rt) {
#pragma unroll
    for (int r = 0; r < 4; ++r) {
      long grow = base_row + wr * 64 + rt * 16 + q * 4 + r;
      if (grow < N_NODES) {
#pragma unroll
        for (int ct = 0; ct < 4; ++ct)
          X1b[grow * HID + wc * 64 + ct * 16 + m16] = f2bf(acc[rt][ct][r]);
      }
    }
  }
}

// ---------------- CSR gather-sum (bf16) + relu -> h1 bf16 ----------------
__global__ __launch_bounds__(256) void agg_relu_k(
    const u16* __restrict__ X1b, const int* __restrict__ row_ofs,
    const int* __restrict__ csr, const float* __restrict__ in_is,
    u16* __restrict__ h1b) {
  int d = blockIdx.x * 4 + (threadIdx.x >> 6);  // exact: 25000*4 = N
  int lane = threadIdx.x & 63;
  int half = lane >> 5;
  int col = (lane & 31) * 8;
  int beg = row_ofs[d], end = row_ofs[d + 1];
  float a[8];
#pragma unroll
  for (int i = 0; i < 8; ++i) a[i] = 0.0f;
  int j = beg + half;
  for (; j + 14 < end; j += 16) {
    int s0 = csr[j],      s1 = csr[j + 2],  s2 = csr[j + 4],  s3 = csr[j + 6];
    int s4 = csr[j + 8],  s5 = csr[j + 10], s6 = csr[j + 12], s7 = csr[j + 14];
    uint4 v0 = *(const uint4*)(X1b + (size_t)s0 * HID + col);
    uint4 v1 = *(const uint4*)(X1b + (size_t)s1 * HID + col);
    uint4 v2 = *(const uint4*)(X1b + (size_t)s2 * HID + col);
    uint4 v3 = *(const uint4*)(X1b + (size_t)s3 * HID + col);
    uint4 v4 = *(const uint4*)(X1b + (size_t)s4 * HID + col);
    uint4 v5 = *(const uint4*)(X1b + (size_t)s5 * HID + col);
    uint4 v6 = *(const uint4*)(X1b + (size_t)s6 * HID + col);
    uint4 v7 = *(const uint4*)(X1b + (size_t)s7 * HID + col);
    acc8(a, v0); acc8(a, v1); acc8(a, v2); acc8(a, v3);
    acc8(a, v4); acc8(a, v5); acc8(a, v6); acc8(a, v7);
  }
  for (; j + 6 < end; j += 8) {
    int s0 = csr[j], s1 = csr[j + 2], s2 = csr[j + 4], s3 = csr[j + 6];
    uint4 v0 = *(const uint4*)(X1b + (size_t)s0 * HID + col);
    uint4 v1 = *(const uint4*)(X1b + (size_t)s1 * HID + col);
    uint4 v2 = *(const uint4*)(X1b + (size_t)s2 * HID + col);
    uint4 v3 = *(const uint4*)(X1b + (size_t)s3 * HID + col);
    acc8(a, v0); acc8(a, v1); acc8(a, v2); acc8(a, v3);
  }
  for (; j < end; j += 2) {
    uint4 v0 = *(const uint4*)(X1b + (size_t)csr[j] * HID + col);
    acc8(a, v0);
  }
#pragma unroll
  for (int i = 0; i < 8; ++i) a[i] += __shfl(a[i], lane ^ 32, 64);
  if (half == 0) {
    float is = in_is[d];
    u16 o[8];
#pragma unroll
    for (int i = 0; i < 8; ++i) o[i] = f2bf(fmaxf(a[i] * is, 0.0f));
    uint4 pk;
    pk.x = (uint32_t)o[0] | ((uint32_t)o[1] << 16);
    pk.y = (uint32_t)o[2] | ((uint32_t)o[3] << 16);
    pk.z = (uint32_t)o[4] | ((uint32_t)o[5] << 16);
    pk.w = (uint32_t)o[6] | ((uint32_t)o[7] << 16);
    *(uint4*)(h1b + (size_t)d * HID + col) = pk;
  }
}

// ---------------- BatchNorm stats (bf16 in, fp32 accumulate), vectorized ----------------
__global__ __launch_bounds__(256) void bn_stats_k(const u16* __restrict__ h1b,
                                                  float* __restrict__ bn) {
  __shared__ float ls[512];
  const int tid = threadIdx.x;
  const int cb = (tid & 31) * 8;   // col base
  const int ms = tid >> 5;         // row-stream 0..7
  float s[8], s2[8];
#pragma unroll
  for (int i = 0; i < 8; ++i) { s[i] = 0.f; s2[i] = 0.f; }
  for (int m = ms;; m += 8) {
    int r = blockIdx.x + 256 * m;
    if (r >= N_NODES) break;
    uint4 v = *(const uint4*)(h1b + (size_t)r * HID + cb);
    float f[8];
    f[0] = bf2f((u16)(v.x & 0xffffu)); f[1] = bf2f((u16)(v.x >> 16));
    f[2] = bf2f((u16)(v.y & 0xffffu)); f[3] = bf2f((u16)(v.y >> 16));
    f[4] = bf2f((u16)(v.z & 0xffffu)); f[5] = bf2f((u16)(v.z >> 16));
    f[6] = bf2f((u16)(v.w & 0xffffu)); f[7] = bf2f((u16)(v.w >> 16));
#pragma unroll
    for (int i = 0; i < 8; ++i) { s[i] += f[i]; s2[i] += f[i] * f[i]; }
  }
  ls[tid] = 0.f; ls[tid + 256] = 0.f;
  __syncthreads();
#pragma unroll
  for (int i = 0; i < 8; ++i) {
    atomicAdd(&ls[cb + i], s[i]);
    atomicAdd(&ls[256 + cb + i], s2[i]);
  }
  __syncthreads();
  atomicAdd(&bn[tid], ls[tid]);
  atomicAdd(&bn[HID + tid], ls[256 + tid]);
}

__global__ void bn_fin_k(float* __restrict__ bn) {
  int c = threadIdx.x;
  float mean = bn[c] / (float)N_NODES;
  float var = bn[HID + c] / (float)N_NODES - mean * mean;
  float istd = rsqrtf(var + 1e-5f);
  bn[512 + c] = istd;           // cB
  bn[768 + c] = -mean * istd;   // cA:  normalized = h*cB + cA
}

// ---------------- GEMM2/3 (MFMA): XMLV[row] = [mu(16) | logvar(16)] bf16 ----------------
#define WLS 264   // u16 row stride for Wls: dword-stride 132 -> 2-way bank alias (free)
__global__ __launch_bounds__(256) void gemm23_k(
    const u16* __restrict__ h1b, const u16* __restrict__ Wt23,
    const uint32_t* __restrict__ mask2a, const uint32_t* __restrict__ mask2b,
    const float* __restrict__ out_is, const float* __restrict__ bn,
    u16* __restrict__ XMLV) {
  __shared__ u16 Wls[32 * WLS];
  __shared__ float cB[HID], cA[HID];
  const int tid = threadIdx.x;
#pragma unroll
  for (int i = 0; i < 4; ++i) {   // stage Wt23 (16KB) into padded LDS
    int idx = tid + i * 256;      // 1024 uint4 chunks
    int n = idx >> 5, c = idx & 31;
    *(uint4*)(Wls + n * WLS + c * 8) = ((const uint4*)Wt23)[idx];
  }
  cB[tid] = bn[512 + tid];
  cA[tid] = bn[768 + tid];
  __syncthreads();

  const int wv = tid >> 6, lane = tid & 63;
  const int m = lane & 15, q = lane >> 4;
  const long arow = (long)blockIdx.x * 64 + wv * 16 + m;   // A row this lane loads
  const bool valid = arow < N_NODES;
  const float osc = valid ? 2.0f * out_is[arow] : 0.0f;

  float4v accM = (float4v)0.0f, accL = (float4v)0.0f;
  for (int kc = 0; kc < HID; kc += 32) {
    const int kof = kc + q * 8;
    uint4 hv = make_uint4(0, 0, 0, 0);
    uint32_t wa = 0, wb = 0;
    if (valid) {
      hv = *(const uint4*)(h1b + arow * HID + kof);
      uint32_t widx = ((uint32_t)arow * HID + (uint32_t)kc) >> 5;
      wa = mask2a[widx] >> (q * 8);
      wb = mask2b[widx] >> (q * 8);
    }
    float4 B0 = *(const float4*)(cB + kof);
    float4 B1 = *(const float4*)(cB + kof + 4);
    float4 A0 = *(const float4*)(cA + kof);
    float4 A1 = *(const float4*)(cA + kof + 4);
    float hval[8] = {
      bf2f((u16)(hv.x & 0xffffu)), bf2f((u16)(hv.x >> 16)),
      bf2f((u16)(hv.y & 0xffffu)), bf2f((u16)(hv.y >> 16)),
      bf2f((u16)(hv.z & 0xffffu)), bf2f((u16)(hv.z >> 16)),
      bf2f((u16)(hv.w & 0xffffu)), bf2f((u16)(hv.w >> 16))};
    float nb[8] = {B0.x, B0.y, B0.z, B0.w, B1.x, B1.y, B1.z, B1.w};
    float na[8] = {A0.x, A0.y, A0.z, A0.w, A1.x, A1.y, A1.z, A1.w};
    short8 Aa, Ab;
#pragma unroll
    for (int jj = 0; jj < 8; ++jj) {
      float t = fmaf(hval[jj], nb[jj], na[jj]) * osc;
      u16 tb = f2bf(t);
      Aa[jj] = (short)(((wa >> jj) & 1u) ? tb : 0);
      Ab[jj] = (short)(((wb >> jj) & 1u) ? tb : 0);
    }
    short8 Bm = *(const short8*)(Wls + m * WLS + kof);          // W2 col m
    short8 Bl = *(const short8*)(Wls + (16 + m) * WLS + kof);   // W3 col m
    accM = __builtin_amdgcn_mfma_f32_16x16x32_bf16(Aa, Bm, accM, 0, 0, 0);
    accL = __builtin_amdgcn_mfma_f32_16x16x32_bf16(Ab, Bl, accL, 0, 0, 0);
  }
  // D: row = q*4+r, col = m
#pragma unroll
  for (int r = 0; r < 4; ++r) {
    long srow = (long)blockIdx.x * 64 + wv * 16 + q * 4 + r;
    if (srow < N_NODES) {
      XMLV[srow * 32 + m]      = f2bf(accM[r]);
      XMLV[srow * 32 + 16 + m] = f2bf(accL[r]);
    }
  }
}

// ---------------- final: aggregate interleaved mu|logvar + reparameterize ----------------
__global__ __launch_bounds__(256) void agg_final_k(
    const u16* __restrict__ XMLV, const int* __restrict__ row_ofs,
    const int* __restrict__ csr, const float* __restrict__ in_is,
    uint32_t ke0, uint32_t ke1, float* __restrict__ out) {
  int g = blockIdx.x * 4 + (threadIdx.x >> 6);  // exact: 25000*4 = N
  int lane = threadIdx.x & 63;
  int half = lane >> 5, c = lane & 31;
  int beg = row_ofs[g], end = row_ofs[g + 1];
  float s = 0.f;
  int j = beg + half;
  for (; j + 14 < end; j += 16) {
    int s0 = csr[j],      s1 = csr[j + 2],  s2 = csr[j + 4],  s3 = csr[j + 6];
    int s4 = csr[j + 8],  s5 = csr[j + 10], s6 = csr[j + 12], s7 = csr[j + 14];
    float v0 = bf2f(XMLV[(size_t)s0 * 32 + c]);
    float v1 = bf2f(XMLV[(size_t)s1 * 32 + c]);
    float v2 = bf2f(XMLV[(size_t)s2 * 32 + c]);
    float v3 = bf2f(XMLV[(size_t)s3 * 32 + c]);
    float v4 = bf2f(XMLV[(size_t)s4 * 32 + c]);
    float v5 = bf2f(XMLV[(size_t)s5 * 32 + c]);
    float v6 = bf2f(XMLV[(size_t)s6 * 32 + c]);
    float v7 = bf2f(XMLV[(size_t)s7 * 32 + c]);
    s += v0; s += v1; s += v2; s += v3;
    s += v4; s += v5; s += v6; s += v7;
  }
  // fully-predicated tail: <=7 remaining edges per half, all loads independent
#pragma unroll
  for (int k = 0; k < 8; ++k) {
    int e = j + 2 * k;
    if (e < end) s += bf2f(XMLV[(size_t)csr[e] * 32 + c]);
  }
  s += __shfl(s, lane ^ 32, 64);
  if (half == 0) {
    s *= in_is[g];
    float other = __shfl(s, lane ^ 16, 64);  // mu lane c gets logvar from lane c+16
    if (c < 16) {
      uint32_t i = (uint32_t)(g * NCLS + c);
      uint32_t bits = tf_bits32(ke0, ke1, i);
      float f = __uint_as_float((bits >> 9) | 0x3f800000u) - 1.0f;
      const float lo = -0.99999994f;          // nextafter(-1,0)
      float u = fmaxf(lo, fmaf(f, 2.0f, lo)); // (hi-lo) rounds to exactly 2.0f
      float eps = 1.41421356f * erfinv_f32(u);
      out[i] = eps * expf(other) + s;
    }
  }
}

// ---------------- host ----------------
extern "C" void kernel_launch(void* const* d_in, const int* in_sizes, int n_in,
                              void* d_out, int out_size, void* d_ws, size_t ws_size,
                              hipStream_t stream) {
  (void)in_sizes; (void)n_in; (void)out_size; (void)ws_size;
  const float* x  = (const float*)d_in[0];
  const float* W1 = (const float*)d_in[1];
  const float* W2 = (const float*)d_in[2];
  const float* W3 = (const float*)d_in[3];
  const int* esrc = (const int*)d_in[4];
  const int* edst = (const int*)d_in[5];
  float* out = (float*)d_out;

  uint32_t kb[8];
  for (int j = 0; j < 4; ++j)
    threefry2x32(0u, 42u, 0u, (uint32_t)j, kb[2 * j], kb[2 * j + 1]);
  // k1=(kb0,kb1) drop-x; k2a=(kb2,kb3); k2b=(kb4,kb5); keps=(kb6,kb7)

  char* p = (char*)d_ws;
  auto take = [&](size_t bytes) -> void* {
    void* r = (void*)p;
    p += (bytes + 255) & ~(size_t)255;
    return r;
  };
  u16* Xb        = (u16*)take(sizeof(u16) * (size_t)N_NODES * IN_DIM);   // 102.4 MB
  u16* X1b       = (u16*)take(sizeof(u16) * (size_t)N_NODES * HID);
  u16* h1b       = (u16*)take(sizeof(u16) * (size_t)N_NODES * HID);
  u16* XMLV      = (u16*)take(sizeof(u16) * (size_t)N_NODES * 32);
  u16* W1t       = (u16*)take(sizeof(u16) * (size_t)IN_DIM * HID);
  u16* Wt23      = (u16*)take(sizeof(u16) * 32 * HID);
  uint32_t* mask2a = (uint32_t*)take((size_t)N_NODES * HID / 8);
  uint32_t* mask2b = (uint32_t*)take((size_t)N_NODES * HID / 8);
  int* in_deg    = (int*)take(sizeof(int) * N_NODES);
  float* out_is  = (float*)take(sizeof(float) * N_NODES);
  float* in_is   = (float*)take(sizeof(float) * N_NODES);
  int* row_ofs   = (int*)take(sizeof(int) * (N_NODES + 1));
  int* csr       = (int*)take(sizeof(int) * N_EDGES);
  float* bn      = (float*)take(sizeof(float) * 1024);

  // P16 partials [DBLK][N_NODES] u16 = 51.2 MB, aliased onto Xb (consumed before cast_x)
  u16* P16 = (u16*)Xb;

  hipMemsetAsync(bn, 0, sizeof(float) * 512, stream);

  hist_k<<<DBLK, 1024, 0, stream>>>(esrc, edst, P16);
  degsum_k<<<(N_NODES + 255) / 256, 256, 0, stream>>>(P16, in_deg, out_is, in_is);
  scan_offsets_k<<<1, 1024, 0, stream>>>(in_deg, row_ofs);
  place_k<<<DBLK, 1024, 0, stream>>>(esrc, edst, P16, row_ofs, csr);

  gen_mask2_k<<<(N_NODES * HID) / 256, 256, 0, stream>>>(kb[2], kb[3], kb[4], kb[5],
                                                         mask2a, mask2b);

  cast_w_k<<<(IN_DIM * HID + 32 * HID) / 256, 256, 0, stream>>>(W1, W2, W3, W1t, Wt23);
  cast_x_k<<<(N_NODES * IN_DIM / 8) / 256, 256, 0, stream>>>(x, out_is, kb[0], kb[1], Xb);

  gemm1_k<<<(N_NODES + G1_BM - 1) / G1_BM, 512, 0, stream>>>(Xb, W1t, X1b);
  agg_relu_k<<<N_NODES / 4, 256, 0, stream>>>(X1b, row_ofs, csr, in_is, h1b);
  bn_stats_k<<<256, 256, 0, stream>>>(h1b, bn);
  bn_fin_k<<<1, 256, 0, stream>>>(bn);
  gemm23_k<<<(N_NODES + 63) / 64, 256, 0, stream>>>(h1b, Wt23, mask2a, mask2b, out_is, bn, XMLV);
  agg_final_k<<<N_NODES / 4, 256, 0, stream>>>(XMLV, row_ofs, csr, in_is, kb[6], kb[7], out);
}